// Round 13
// baseline (71.249 us; speedup 1.0000x reference)
//
#include <hip/hip_runtime.h>
#include <hip/hip_fp16.h>

// GCN layer: out[N,16] = segment_sum(vals[e] * embeds[col[e], :], row[e])
// Round 13: five invariances (fetch bytes r3/r4, MLP r5/r10, addr count r11,
// occupancy r12) leave one candidate bound: per-CU L1 line-FILL throughput --
// every gather allocates an L1 line that is ~never reused (32KB L1 vs 3.2MB
// table). One change vs r11: table gathers use __builtin_nontemporal_load
// (nt = no-allocate) to take L1 fills off the critical path.

#define D 16
constexpr int BLOCK = 256;
constexpr int NPB = 64;        // nodes per block (4 lanes/node)
constexpr int SMEM_E = 3072;   // staged edges per window (r11 config)

typedef float f32x4 __attribute__((ext_vector_type(4)));
typedef int   i32x4 __attribute__((ext_vector_type(4)));
typedef unsigned int u32x4 __attribute__((ext_vector_type(4)));

// Pad-swizzle: +4 u32 per 64 logical u32 -> cross-group broadcast ds_reads
// spread across banks; 16-u32 batch runs at 16-multiples never cross a pad.
__device__ __forceinline__ unsigned cvIdx(unsigned i) { return i + ((i >> 6) << 2); }

__device__ __forceinline__ float2 h2f(unsigned u) {
  union { unsigned u; __half2 h; } c; c.u = u;
  return __half22float2(c.h);
}

// Fused prep: repack embeds f32->f16 (task A) + row_ptr adjacent-diff (task B).
__global__ __launch_bounds__(BLOCK) void prep_kernel(
    const int* __restrict__ row, int E,
    const float* __restrict__ embeds, int N,
    int* __restrict__ row_ptr, __half* __restrict__ table) {
  const long long t = (long long)blockIdx.x * BLOCK + threadIdx.x;

  if (table != nullptr) {
    if (t < (long long)N * 2) {   // 8 halves per thread
      const f32x4* src = (const f32x4*)embeds + t * 2;
      f32x4 a = src[0];
      f32x4 b = src[1];
      union { __half2 h[4]; u32x4 u; } o;
      o.h[0] = __floats2half2_rn(a[0], a[1]);
      o.h[1] = __floats2half2_rn(a[2], a[3]);
      o.h[2] = __floats2half2_rn(b[0], b[1]);
      o.h[3] = __floats2half2_rn(b[2], b[3]);
      *((u32x4*)table + t) = o.u;
    }
  }

  const long long e = t * 4;
  if (e < E) {
    int prev = (e == 0) ? -1 : row[e - 1];
    const int cnt = (E - e >= 4) ? 4 : (int)(E - e);
    int r[4];
    if (cnt == 4) {
      i32x4 r4 = *(const i32x4*)(row + e);
      r[0] = r4[0]; r[1] = r4[1]; r[2] = r4[2]; r[3] = r4[3];
    } else {
      for (int k = 0; k < cnt; ++k) r[k] = row[e + k];
    }
    for (int k = 0; k < cnt; ++k) {
      for (int n = prev + 1; n <= r[k]; ++n) row_ptr[n] = (int)e + k;
      prev = r[k];
    }
    if (e + cnt == E) {
      for (int n = prev + 1; n <= N; ++n) row_ptr[n] = E;
    }
  }
}

__global__ __launch_bounds__(BLOCK) void gcn_half_kernel(
    const int* __restrict__ col, const float* __restrict__ vals,
    const __half* __restrict__ table, const int* __restrict__ row_ptr,
    float* __restrict__ out, int N, int E) {
  __shared__ __align__(16) unsigned s_cv[SMEM_E * 2 + (SMEM_E * 2 / 64) * 4];

  const int t = threadIdx.x;
  const int n0 = blockIdx.x * NPB;
  const int nEnd = (n0 + NPB < N) ? n0 + NPB : N;
  const int g = t >> 2;                 // group = node
  const unsigned l = (unsigned)(t & 3);
  const unsigned s = l >> 1;            // edge parity this lane consumes
  const unsigned h16 = (l & 1) << 4;    // byte offset of this lane's 16B half
  const int node = n0 + g;
  const bool active = (node < nEnd);

  const int Wb = row_ptr[n0] & ~3;
  const int We = row_ptr[nEnd];
  const int beg = active ? row_ptr[node] : 0;
  const int end = active ? row_ptr[node + 1] : 0;
  const char* tb = (const char*)table;

  float acc[8] = {0.f, 0.f, 0.f, 0.f, 0.f, 0.f, 0.f, 0.f};

  for (int W0 = Wb; W0 < We; W0 += SMEM_E) {
    const int cnt  = (SMEM_E < We - W0) ? SMEM_E : (We - W0);
    const int cntP = (cnt + 7) & ~7;
    __syncthreads();
    // Cooperative coalesced staging: 4 edges/thread/pass, 3 passes.
    for (int i = t * 4; i < cntP; i += BLOCK * 4) {
      const int e = W0 + i;
      unsigned c[4], v[4];
      if (e + 3 < E) {
        i32x4 c4 = *(const i32x4*)(col + e);
        f32x4 v4 = *(const f32x4*)(vals + e);
        #pragma unroll
        for (int k = 0; k < 4; ++k) {
          c[k] = (unsigned)c4[k];
          v[k] = __float_as_uint(v4[k]);
        }
      } else {
        #pragma unroll
        for (int k = 0; k < 4; ++k) {
          const bool ok = (e + k < E);
          c[k] = ok ? (unsigned)col[e + k] : 0u;
          v[k] = ok ? __float_as_uint(vals[e + k]) : 0u;
        }
      }
      *(u32x4*)(s_cv + cvIdx((unsigned)i * 2))     = (u32x4){c[0], v[0], c[1], v[1]};
      *(u32x4*)(s_cv + cvIdx((unsigned)i * 2) + 4) = (u32x4){c[2], v[2], c[3], v[3]};
    }
    __syncthreads();

    const int gb = (beg > W0) ? beg : W0;
    const int ge = (end < W0 + cnt) ? end : (W0 + cnt);
    if (ge > gb) {
      const unsigned span = (unsigned)(ge - gb);
      const int e0 = W0 + ((gb - W0) & ~7);
      const int e1 = e0 + ((ge - e0 + 7) & ~7);   // <= W0 + cntP

      for (int e = e0; e < e1; e += 8) {
        const unsigned ci = cvIdx((unsigned)(e - W0) * 2);
        // Metadata via LDS broadcast (lgkmcnt): M[k] = {c2k,v2k,c2k+1,v2k+1}.
        u32x4 M0 = *(const u32x4*)(s_cv + ci);
        u32x4 M1 = *(const u32x4*)(s_cv + ci + 4);
        u32x4 M2 = *(const u32x4*)(s_cv + ci + 8);
        u32x4 M3 = *(const u32x4*)(s_cv + ci + 12);
        // 4 dwordx4 NONTEMPORAL gathers (no L1 allocate): lane handles edge
        // e+2k+s, 16B half h -> 2 addr/edge, 1 L2 line/edge.
        const unsigned c0 = M0[s << 1], w0b = M0[(s << 1) + 1];
        const unsigned c1 = M1[s << 1], w1b = M1[(s << 1) + 1];
        const unsigned c2 = M2[s << 1], w2b = M2[(s << 1) + 1];
        const unsigned c3 = M3[s << 1], w3b = M3[(s << 1) + 1];
        u32x4 G0 = __builtin_nontemporal_load((const u32x4*)(tb + ((size_t)c0 << 5) + h16));
        u32x4 G1 = __builtin_nontemporal_load((const u32x4*)(tb + ((size_t)c1 << 5) + h16));
        u32x4 G2 = __builtin_nontemporal_load((const u32x4*)(tb + ((size_t)c2 << 5) + h16));
        u32x4 G3 = __builtin_nontemporal_load((const u32x4*)(tb + ((size_t)c3 << 5) + h16));
#define EDGE(k, GG, wb)                                                     \
        {                                                                   \
          const float w = ((unsigned)(e + 2 * k + (int)s - gb) < span)      \
                              ? __uint_as_float(wb) : 0.f;                  \
          const float2 f0 = h2f(GG[0]), f1 = h2f(GG[1]);                    \
          const float2 f2 = h2f(GG[2]), f3 = h2f(GG[3]);                    \
          acc[0] = fmaf(w, f0.x, acc[0]);                                   \
          acc[1] = fmaf(w, f0.y, acc[1]);                                   \
          acc[2] = fmaf(w, f1.x, acc[2]);                                   \
          acc[3] = fmaf(w, f1.y, acc[3]);                                   \
          acc[4] = fmaf(w, f2.x, acc[4]);                                   \
          acc[5] = fmaf(w, f2.y, acc[5]);                                   \
          acc[6] = fmaf(w, f3.x, acc[6]);                                   \
          acc[7] = fmaf(w, f3.y, acc[7]);                                   \
        }
        EDGE(0, G0, w0b)
        EDGE(1, G1, w1b)
        EDGE(2, G2, w2b)
        EDGE(3, G3, w3b)
#undef EDGE
      }
    }
  }

  // Combine the two edge-parities: lane l += lane l^2.
  #pragma unroll
  for (int j = 0; j < 8; ++j) acc[j] += __shfl_xor(acc[j], 2, 64);

  if (active && s == 0) {  // lanes 0,1 store their 8 features (32B each)
    float* p = out + (size_t)node * D + (l & 1) * 8;
    f32x4 lo = {acc[0], acc[1], acc[2], acc[3]};
    f32x4 hi = {acc[4], acc[5], acc[6], acc[7]};
    __builtin_nontemporal_store(lo, (f32x4*)p);
    __builtin_nontemporal_store(hi, (f32x4*)(p + 4));
  }
}

// Fallback (f32 gathers straight from embeds) if ws can't hold the table.
__global__ __launch_bounds__(BLOCK) void gcn_node_f32_kernel(
    const int* __restrict__ col, const float* __restrict__ vals,
    const f32x4* __restrict__ embeds4, const int* __restrict__ row_ptr,
    f32x4* __restrict__ out4, int N, int E) {
  const int t = blockIdx.x * BLOCK + threadIdx.x;
  const int node = t >> 2;
  const int q = t & 3;
  if (node >= N) return;
  const int beg = row_ptr[node];
  const int end = row_ptr[node + 1];
  f32x4 acc = {0.f, 0.f, 0.f, 0.f};
  for (int e = beg; e < end; ++e) {
    acc += vals[e] * embeds4[(long long)col[e] * 4 + q];
  }
  __builtin_nontemporal_store(acc, out4 + (long long)node * 4 + q);
}

extern "C" void kernel_launch(void* const* d_in, const int* in_sizes, int n_in,
                              void* d_out, int out_size, void* d_ws, size_t ws_size,
                              hipStream_t stream) {
  const int*   row    = (const int*)d_in[0];
  const int*   col    = (const int*)d_in[1];
  const float* vals   = (const float*)d_in[2];
  const float* embeds = (const float*)d_in[3];

  const int E = in_sizes[0];
  const int N = in_sizes[3] / D;

  const size_t rp_bytes  = ((size_t)(N + 1) * 4 + 511) & ~(size_t)511;
  const size_t tbl_bytes = (size_t)N * D * sizeof(__half);
  const bool use_half = (ws_size >= rp_bytes + tbl_bytes) && (E >= 8);

  int*    row_ptr = (int*)d_ws;
  __half* table   = use_half ? (__half*)((char*)d_ws + rp_bytes) : nullptr;

  {
    long long chunksB = ((long long)E + 3) / 4;
    long long chunksA = use_half ? (long long)N * 2 : 0;
    long long threads = chunksB > chunksA ? chunksB : chunksA;
    int grid = (int)((threads + BLOCK - 1) / BLOCK);
    prep_kernel<<<grid, BLOCK, 0, stream>>>(row, E, embeds, N, row_ptr, table);
  }
  if (use_half) {
    const int grid = (N + NPB - 1) / NPB;
    gcn_half_kernel<<<grid, BLOCK, 0, stream>>>(
        col, vals, table, row_ptr, (float*)d_out, N, E);
  } else {
    long long threads = (long long)N * 4;
    int grid = (int)((threads + BLOCK - 1) / BLOCK);
    gcn_node_f32_kernel<<<grid, BLOCK, 0, stream>>>(
        col, vals, (const f32x4*)embeds, row_ptr, (f32x4*)d_out, N, E);
  }
}

// Round 14
// 37.140 us; speedup vs baseline: 1.9184x; 1.9184x over previous
//
#include <hip/hip_runtime.h>
#include <hip/hip_fp16.h>

// GCN layer: out[N,16] = segment_sum(vals[e] * embeds[col[e], :], row[e])
// Round 14: converged model -- K2 is bound by L2 line-requests x latency /
// per-CU MSHR capacity (~64): ~12.5K lines/CU * 1.22 padding * 300cy/64
// = 72K cy = measured 30us. Bytes/MLP/addr/occupancy all proven invariant.
// Only lever left: the 22% padded requests. This round: drop pad-swizzle
// (r6 measured 0 conflicts without it) -> head alignment 8->2 edges, plus
// 8 zeroed guard slots after the window so tail over-read is safe (w=0,c=0).

#define D 16
constexpr int BLOCK = 256;
constexpr int NPB = 64;        // nodes per block (4 lanes/node)
constexpr int SMEM_E = 3072;   // staged edges per window

typedef float f32x4 __attribute__((ext_vector_type(4)));
typedef int   i32x4 __attribute__((ext_vector_type(4)));
typedef unsigned int u32x4 __attribute__((ext_vector_type(4)));

__device__ __forceinline__ float2 h2f(unsigned u) {
  union { unsigned u; __half2 h; } c; c.u = u;
  return __half22float2(c.h);
}

// Fused prep: repack embeds f32->f16 (task A) + row_ptr adjacent-diff (task B).
__global__ __launch_bounds__(BLOCK) void prep_kernel(
    const int* __restrict__ row, int E,
    const float* __restrict__ embeds, int N,
    int* __restrict__ row_ptr, __half* __restrict__ table) {
  const long long t = (long long)blockIdx.x * BLOCK + threadIdx.x;

  if (table != nullptr) {
    if (t < (long long)N * 2) {   // 8 halves per thread
      const f32x4* src = (const f32x4*)embeds + t * 2;
      f32x4 a = src[0];
      f32x4 b = src[1];
      union { __half2 h[4]; u32x4 u; } o;
      o.h[0] = __floats2half2_rn(a[0], a[1]);
      o.h[1] = __floats2half2_rn(a[2], a[3]);
      o.h[2] = __floats2half2_rn(b[0], b[1]);
      o.h[3] = __floats2half2_rn(b[2], b[3]);
      *((u32x4*)table + t) = o.u;
    }
  }

  const long long e = t * 4;
  if (e < E) {
    int prev = (e == 0) ? -1 : row[e - 1];
    const int cnt = (E - e >= 4) ? 4 : (int)(E - e);
    int r[4];
    if (cnt == 4) {
      i32x4 r4 = *(const i32x4*)(row + e);
      r[0] = r4[0]; r[1] = r4[1]; r[2] = r4[2]; r[3] = r4[3];
    } else {
      for (int k = 0; k < cnt; ++k) r[k] = row[e + k];
    }
    for (int k = 0; k < cnt; ++k) {
      for (int n = prev + 1; n <= r[k]; ++n) row_ptr[n] = (int)e + k;
      prev = r[k];
    }
    if (e + cnt == E) {
      for (int n = prev + 1; n <= N; ++n) row_ptr[n] = E;
    }
  }
}

__global__ __launch_bounds__(BLOCK) void gcn_half_kernel(
    const int* __restrict__ col, const float* __restrict__ vals,
    const __half* __restrict__ table, const int* __restrict__ row_ptr,
    float* __restrict__ out, int N, int E) {
  // Linear layout (no pad-swizzle; r6 measured 0 conflicts) + 16 u32 guard
  // (8 zeroed edge slots) so tail batches may over-read safely.
  __shared__ __align__(16) unsigned s_cv[SMEM_E * 2 + 16];

  const int t = threadIdx.x;
  const int n0 = blockIdx.x * NPB;
  const int nEnd = (n0 + NPB < N) ? n0 + NPB : N;
  const int g = t >> 2;                 // group = node
  const unsigned l = (unsigned)(t & 3);
  const unsigned s = l >> 1;            // edge parity this lane consumes
  const unsigned h16 = (l & 1) << 4;    // byte offset of this lane's 16B half
  const int node = n0 + g;
  const bool active = (node < nEnd);

  const int Wb = row_ptr[n0] & ~3;
  const int We = row_ptr[nEnd];
  const int beg = active ? row_ptr[node] : 0;
  const int end = active ? row_ptr[node + 1] : 0;
  const char* tb = (const char*)table;

  float acc[8] = {0.f, 0.f, 0.f, 0.f, 0.f, 0.f, 0.f, 0.f};

  for (int W0 = Wb; W0 < We; W0 += SMEM_E) {
    const int cnt  = (SMEM_E < We - W0) ? SMEM_E : (We - W0);
    const int cntP = (cnt + 7) & ~7;
    __syncthreads();
    // Cooperative coalesced staging: 4 edges/thread/pass, 3 passes.
    for (int i = t * 4; i < cntP; i += BLOCK * 4) {
      const int e = W0 + i;
      unsigned c[4], v[4];
      if (e + 3 < E) {
        i32x4 c4 = *(const i32x4*)(col + e);
        f32x4 v4 = *(const f32x4*)(vals + e);
        #pragma unroll
        for (int k = 0; k < 4; ++k) {
          c[k] = (unsigned)c4[k];
          v[k] = __float_as_uint(v4[k]);
        }
      } else {
        #pragma unroll
        for (int k = 0; k < 4; ++k) {
          const bool ok = (e + k < E);
          c[k] = ok ? (unsigned)col[e + k] : 0u;
          v[k] = ok ? __float_as_uint(vals[e + k]) : 0u;
        }
      }
      *(u32x4*)(s_cv + (unsigned)i * 2)     = (u32x4){c[0], v[0], c[1], v[1]};
      *(u32x4*)(s_cv + (unsigned)i * 2 + 4) = (u32x4){c[2], v[2], c[3], v[3]};
    }
    if (t < 4) {  // zero the 8-edge guard region past the staged window
      *(u32x4*)(s_cv + (unsigned)cntP * 2 + (unsigned)t * 4) =
          (u32x4){0u, 0u, 0u, 0u};
    }
    __syncthreads();

    const int gb = (beg > W0) ? beg : W0;
    const int ge = (end < W0 + cnt) ? end : (W0 + cnt);
    if (ge > gb) {
      const unsigned span = (unsigned)(ge - gb);
      // Head aligned to 2 edges (16B metadata alignment), not 8: padding
      // drops from ~7 to ~4 wasted gathers per node (-8% line requests).
      const int e0 = W0 + ((gb - W0) & ~1);
      const int e1 = e0 + ((ge - e0 + 7) & ~7);   // <= W0 + cntP + 7 (guarded)

      for (int e = e0; e < e1; e += 8) {
        const unsigned ci = (unsigned)(e - W0) * 2;
        // Metadata via LDS broadcast (lgkmcnt): M[k] = {c2k,v2k,c2k+1,v2k+1}.
        u32x4 M0 = *(const u32x4*)(s_cv + ci);
        u32x4 M1 = *(const u32x4*)(s_cv + ci + 4);
        u32x4 M2 = *(const u32x4*)(s_cv + ci + 8);
        u32x4 M3 = *(const u32x4*)(s_cv + ci + 12);
        // 4 dwordx4 gathers: lane handles edge e+2k+s, half h (2 addr/edge).
        const unsigned c0 = M0[s << 1], w0b = M0[(s << 1) + 1];
        const unsigned c1 = M1[s << 1], w1b = M1[(s << 1) + 1];
        const unsigned c2 = M2[s << 1], w2b = M2[(s << 1) + 1];
        const unsigned c3 = M3[s << 1], w3b = M3[(s << 1) + 1];
        u32x4 G0 = *(const u32x4*)(tb + ((size_t)c0 << 5) + h16);
        u32x4 G1 = *(const u32x4*)(tb + ((size_t)c1 << 5) + h16);
        u32x4 G2 = *(const u32x4*)(tb + ((size_t)c2 << 5) + h16);
        u32x4 G3 = *(const u32x4*)(tb + ((size_t)c3 << 5) + h16);
#define EDGE(k, GG, wb)                                                     \
        {                                                                   \
          const float w = ((unsigned)(e + 2 * k + (int)s - gb) < span)      \
                              ? __uint_as_float(wb) : 0.f;                  \
          const float2 f0 = h2f(GG[0]), f1 = h2f(GG[1]);                    \
          const float2 f2 = h2f(GG[2]), f3 = h2f(GG[3]);                    \
          acc[0] = fmaf(w, f0.x, acc[0]);                                   \
          acc[1] = fmaf(w, f0.y, acc[1]);                                   \
          acc[2] = fmaf(w, f1.x, acc[2]);                                   \
          acc[3] = fmaf(w, f1.y, acc[3]);                                   \
          acc[4] = fmaf(w, f2.x, acc[4]);                                   \
          acc[5] = fmaf(w, f2.y, acc[5]);                                   \
          acc[6] = fmaf(w, f3.x, acc[6]);                                   \
          acc[7] = fmaf(w, f3.y, acc[7]);                                   \
        }
        EDGE(0, G0, w0b)
        EDGE(1, G1, w1b)
        EDGE(2, G2, w2b)
        EDGE(3, G3, w3b)
#undef EDGE
      }
    }
  }

  // Combine the two edge-parities: lane l += lane l^2.
  #pragma unroll
  for (int j = 0; j < 8; ++j) acc[j] += __shfl_xor(acc[j], 2, 64);

  if (active && s == 0) {  // lanes 0,1 store their 8 features (32B each)
    float* p = out + (size_t)node * D + (l & 1) * 8;
    f32x4 lo = {acc[0], acc[1], acc[2], acc[3]};
    f32x4 hi = {acc[4], acc[5], acc[6], acc[7]};
    __builtin_nontemporal_store(lo, (f32x4*)p);
    __builtin_nontemporal_store(hi, (f32x4*)(p + 4));
  }
}

// Fallback (f32 gathers straight from embeds) if ws can't hold the table.
__global__ __launch_bounds__(BLOCK) void gcn_node_f32_kernel(
    const int* __restrict__ col, const float* __restrict__ vals,
    const f32x4* __restrict__ embeds4, const int* __restrict__ row_ptr,
    f32x4* __restrict__ out4, int N, int E) {
  const int t = blockIdx.x * BLOCK + threadIdx.x;
  const int node = t >> 2;
  const int q = t & 3;
  if (node >= N) return;
  const int beg = row_ptr[node];
  const int end = row_ptr[node + 1];
  f32x4 acc = {0.f, 0.f, 0.f, 0.f};
  for (int e = beg; e < end; ++e) {
    acc += vals[e] * embeds4[(long long)col[e] * 4 + q];
  }
  __builtin_nontemporal_store(acc, out4 + (long long)node * 4 + q);
}

extern "C" void kernel_launch(void* const* d_in, const int* in_sizes, int n_in,
                              void* d_out, int out_size, void* d_ws, size_t ws_size,
                              hipStream_t stream) {
  const int*   row    = (const int*)d_in[0];
  const int*   col    = (const int*)d_in[1];
  const float* vals   = (const float*)d_in[2];
  const float* embeds = (const float*)d_in[3];

  const int E = in_sizes[0];
  const int N = in_sizes[3] / D;

  const size_t rp_bytes  = ((size_t)(N + 1) * 4 + 511) & ~(size_t)511;
  const size_t tbl_bytes = (size_t)N * D * sizeof(__half);
  const bool use_half = (ws_size >= rp_bytes + tbl_bytes) && (E >= 8);

  int*    row_ptr = (int*)d_ws;
  __half* table   = use_half ? (__half*)((char*)d_ws + rp_bytes) : nullptr;

  {
    long long chunksB = ((long long)E + 3) / 4;
    long long chunksA = use_half ? (long long)N * 2 : 0;
    long long threads = chunksB > chunksA ? chunksB : chunksA;
    int grid = (int)((threads + BLOCK - 1) / BLOCK);
    prep_kernel<<<grid, BLOCK, 0, stream>>>(row, E, embeds, N, row_ptr, table);
  }
  if (use_half) {
    const int grid = (N + NPB - 1) / NPB;
    gcn_half_kernel<<<grid, BLOCK, 0, stream>>>(
        col, vals, table, row_ptr, (float*)d_out, N, E);
  } else {
    long long threads = (long long)N * 4;
    int grid = (int)((threads + BLOCK - 1) / BLOCK);
    gcn_node_f32_kernel<<<grid, BLOCK, 0, stream>>>(
        col, vals, (const f32x4*)embeds, row_ptr, (f32x4*)d_out, N, E);
  }
}